// Round 13
// baseline (490.008 us; speedup 1.0000x reference)
//
#include <hip/hip_runtime.h>
#include <hip/hip_bf16.h>

// ---------------------------------------------------------------------------
// GraphActorNetwork: movement MLP (16->128->128->128) -> scatter-mean over
// edges -> phase MLP (128->128->128->1).
// Round 13 = round 12 resubmitted (round-12 bench died on infra:
// UnresponsiveContainer before any kernel ran).
// mov_mlp_mfma BARRIER-FREE: each wave owns 16 samples end-to-end (8 cblocks
// x 4 ks = 32 MFMA/layer), LDS is wave-private ping-pong scratch (2x4KB),
// zero __syncthreads -> waves are independent streams. r7-r11 all plateaued
// 165-190us (MfmaUtil ~9%, VALUBusy ~22%, HBM ~11%: barrier-chain stall).
// agg (4-edge ILP), CSR build, phase MLP unchanged from round 11 (378us).
// ---------------------------------------------------------------------------

typedef __attribute__((ext_vector_type(8))) short short8;
typedef __attribute__((ext_vector_type(4))) float f32x4;

union U8 { short8 s8; unsigned int u[4]; };

__device__ __forceinline__ float bf2f(unsigned short u) {
  return __uint_as_float(((unsigned int)u) << 16);
}
__device__ __forceinline__ unsigned short f2bf(float f) {
  unsigned int u = __float_as_uint(f);
  u = (u + 0x7fffu + ((u >> 16) & 1u)) >> 16;   // RNE
  return (unsigned short)u;
}
// compiler-generated packed f32x2 -> bf16x2 (RNE)
__device__ __forceinline__ unsigned int pk2(float a, float b) {
  __hip_bfloat162 h = __float22bfloat162_rn(make_float2(a, b));
  unsigned int u;
  __builtin_memcpy(&u, &h, 4);
  return u;
}

// ---------------- weight prep: f32 -> bf16 transposed -----------------------
// w1t: [128 c][32 k] (k 16..31 zero);  w2t..w5t: [128 c][128 k]
__global__ __launch_bounds__(256)
void prep_weights(const float* __restrict__ W1, const float* __restrict__ W2,
                  const float* __restrict__ W3, const float* __restrict__ W4,
                  const float* __restrict__ W5,
                  unsigned short* __restrict__ w1t, unsigned short* __restrict__ w2t,
                  unsigned short* __restrict__ w3t, unsigned short* __restrict__ w4t,
                  unsigned short* __restrict__ w5t) {
  int t = blockIdx.x * blockDim.x + threadIdx.x;
  int stride = gridDim.x * blockDim.x;
  if (t < 128 * 32) {
    int c = t >> 5, k = t & 31;
    w1t[t] = (k < 16) ? f2bf(W1[k * 128 + c]) : 0;
  }
  for (int i = t; i < 128 * 128; i += stride) {
    int c = i >> 7, k = i & 127;
    w2t[i] = f2bf(W2[k * 128 + c]);
    w3t[i] = f2bf(W3[k * 128 + c]);
    w4t[i] = f2bf(W4[k * 128 + c]);
    w5t[i] = f2bf(W5[k * 128 + c]);
  }
}

// ---------------- movement MLP via MFMA: barrier-free, wave-owned samples ---
// Block: 256 threads = 4 waves. Each wave: 16 samples, all 128 channels.
// Per layer: 8 channel-blocks (2 halves of 4) x 4 ks = 32 MFMA (swapped
// operands: D^T = mfma(Wfrag, actfrag); lane li = sample, acc[cf][i] =
// channel cb*16 + g*4 + i). Act in wave-private LDS ping-pong (16x128 bf16
// = 4KB per buffer), 16B granules XOR-swizzled by (sample&7). No barriers.
__global__ __launch_bounds__(256)
void mov_mlp_mfma(const float* __restrict__ x,
                  const unsigned short* __restrict__ w1t,
                  const unsigned short* __restrict__ w2t,
                  const unsigned short* __restrict__ w3t,
                  const float* __restrict__ b1, const float* __restrict__ b2,
                  const float* __restrict__ b3,
                  unsigned short* __restrict__ hout, int nrows) {
  __shared__ unsigned short sAct[8][2048];   // [wave*2+buf][16 rows x 128 ch] = 32 KB
  const int tid  = threadIdx.x;
  const int lane = tid & 63;
  const int w    = tid >> 6;
  const int li   = lane & 15;     // sample-in-wave
  const int g    = lane >> 4;     // k-group / channel sub-block
  const int row0 = blockIdx.x * 64 + w * 16;

  unsigned short* bufA = sAct[w * 2];
  unsigned short* bufB = sAct[w * 2 + 1];

  // ---- layer 1: x -> bufA (K=32, k 16..31 zero-padded) ----
  {
    short8 Ax;
    {
      U8 a; a.s8 = (short8)0;
      int row = row0 + li;
      if (g < 2 && row < nrows) {
        const float* xp = x + (size_t)row * 16 + g * 8;
        float4 u0 = *(const float4*)xp;
        float4 u1 = *(const float4*)(xp + 4);
        a.u[0] = pk2(u0.x, u0.y); a.u[1] = pk2(u0.z, u0.w);
        a.u[2] = pk2(u1.x, u1.y); a.u[3] = pk2(u1.z, u1.w);
      }
      Ax = a.s8;
    }
#pragma unroll
    for (int ch = 0; ch < 2; ++ch) {
      short8 B1[4];
      f32x4 acc[4];
#pragma unroll
      for (int cf = 0; cf < 4; ++cf) {
        int cb = ch * 4 + cf;
        B1[cf] = *(const short8*)&w1t[(cb * 16 + li) * 32 + g * 8];
        float4 bv = *(const float4*)&b1[cb * 16 + g * 4];
        acc[cf][0] = bv.x; acc[cf][1] = bv.y; acc[cf][2] = bv.z; acc[cf][3] = bv.w;
      }
#pragma unroll
      for (int cf = 0; cf < 4; ++cf)
        acc[cf] = __builtin_amdgcn_mfma_f32_16x16x32_bf16(B1[cf], Ax, acc[cf], 0, 0, 0);
#pragma unroll
      for (int cf = 0; cf < 4; ++cf) {
        int cb = ch * 4 + cf;
        int slot = (cb * 2 + (g >> 1)) ^ (li & 7);
        uint2 u;
        u.x = pk2(fmaxf(acc[cf][0], 0.f), fmaxf(acc[cf][1], 0.f));
        u.y = pk2(fmaxf(acc[cf][2], 0.f), fmaxf(acc[cf][3], 0.f));
        *(uint2*)&bufA[li * 128 + slot * 8 + (g & 1) * 4] = u;
      }
    }
  }

  // ---- layers 2 and 3: wave-private LDS ping-pong, no barriers ----
  const unsigned short* wts[2] = { w2t, w3t };
  const float* bs[2] = { b2, b3 };
#pragma unroll 1
  for (int layer = 0; layer < 2; ++layer) {
    const unsigned short* wt = wts[layer];
    const float* bb = bs[layer];
    unsigned short* src = (layer == 0) ? bufA : bufB;
    unsigned short* dst = (layer == 0) ? bufB : bufA;

    short8 A[4];
#pragma unroll
    for (int ks = 0; ks < 4; ++ks) {
      int slot = (ks * 4 + g) ^ (li & 7);
      A[ks] = *(const short8*)&src[li * 128 + slot * 8];
    }
#pragma unroll
    for (int ch = 0; ch < 2; ++ch) {
      short8 Bf[4][4];   // [cf][ks]
      f32x4 acc[4];
#pragma unroll
      for (int cf = 0; cf < 4; ++cf) {
        int cb = ch * 4 + cf;
        float4 bv = *(const float4*)&bb[cb * 16 + g * 4];
        acc[cf][0] = bv.x; acc[cf][1] = bv.y; acc[cf][2] = bv.z; acc[cf][3] = bv.w;
#pragma unroll
        for (int ks = 0; ks < 4; ++ks)
          Bf[cf][ks] = *(const short8*)&wt[(cb * 16 + li) * 128 + ks * 32 + g * 8];
      }
#pragma unroll
      for (int ks = 0; ks < 4; ++ks)
#pragma unroll
        for (int cf = 0; cf < 4; ++cf)
          acc[cf] = __builtin_amdgcn_mfma_f32_16x16x32_bf16(Bf[cf][ks], A[ks], acc[cf], 0, 0, 0);
#pragma unroll
      for (int cf = 0; cf < 4; ++cf) {
        int cb = ch * 4 + cf;
        int slot = (cb * 2 + (g >> 1)) ^ (li & 7);
        uint2 u;
        u.x = pk2(fmaxf(acc[cf][0], 0.f), fmaxf(acc[cf][1], 0.f));
        u.y = pk2(fmaxf(acc[cf][2], 0.f), fmaxf(acc[cf][3], 0.f));
        *(uint2*)&dst[li * 128 + slot * 8 + (g & 1) * 4] = u;
      }
    }
  }

  // ---- copy-out: bufA (final act) -> hout, 16B/lane x 4, wave-local ----
  {
    int r = lane >> 2;            // 0..15
    int q = lane & 3;
    int grow = row0 + r;
    if (grow < nrows) {
#pragma unroll
      for (int i = 0; i < 4; ++i) {
        int gi = q * 4 + i;
        int slot = gi ^ (r & 7);
        short8 v = *(const short8*)&bufA[r * 128 + slot * 8];
        *(short8*)(hout + (size_t)grow * 128 + gi * 8) = v;
      }
    }
  }
}

// ---------------- CSR build ------------------------------------------------
__global__ __launch_bounds__(256)
void hist_kernel(const int* __restrict__ edst, int* __restrict__ cnt, int ne) {
  int i = blockIdx.x * blockDim.x + threadIdx.x;
  int stride = gridDim.x * blockDim.x;
  for (int e = i; e < ne; e += stride) atomicAdd(cnt + edst[e], 1);
}

// hierarchical scan: 1024 elems per block. s1: per-block sums.
__global__ __launch_bounds__(256)
void scan_sum_kernel(const int* __restrict__ cnt, int* __restrict__ bsum, int nph) {
  __shared__ int red[256];
  const int b = blockIdx.x, t = threadIdx.x;
  const int base = b * 1024 + t * 4;
  int s = 0;
#pragma unroll
  for (int i = 0; i < 4; ++i) {
    int idx = base + i;
    if (idx < nph) s += cnt[idx];
  }
  red[t] = s;
  __syncthreads();
  for (int d = 128; d > 0; d >>= 1) {
    if (t < d) red[t] += red[t + d];
    __syncthreads();
  }
  if (t == 0) bsum[b] = red[0];
}

// s2: exclusive scan of bsum[nb] (nb <= 256) -> boff; total -> *offs_end.
__global__ __launch_bounds__(256)
void scan_top_kernel(const int* __restrict__ bsum, int* __restrict__ boff,
                     int* __restrict__ offs_end, int nb) {
  __shared__ int part[256];
  const int t = threadIdx.x;
  part[t] = (t < nb) ? bsum[t] : 0;
  __syncthreads();
  for (int d = 1; d < 256; d <<= 1) {
    int v = (t >= d) ? part[t - d] : 0;
    __syncthreads();
    part[t] += v;
    __syncthreads();
  }
  if (t < nb) boff[t] = (t == 0) ? 0 : part[t - 1];
  if (t == 255) *offs_end = part[255];
}

// s3: per-block exclusive scan + base offset -> offs, cursor.
__global__ __launch_bounds__(256)
void scan_fill_kernel(const int* __restrict__ cnt, const int* __restrict__ boff,
                      int* __restrict__ offs, int* __restrict__ cursor, int nph) {
  __shared__ int part[256];
  const int b = blockIdx.x, t = threadIdx.x;
  const int base = b * 1024 + t * 4;
  int v[4];
  int s = 0;
#pragma unroll
  for (int i = 0; i < 4; ++i) {
    int idx = base + i;
    v[i] = (idx < nph) ? cnt[idx] : 0;
    s += v[i];
  }
  part[t] = s;
  __syncthreads();
  for (int d = 1; d < 256; d <<= 1) {
    int u = (t >= d) ? part[t - d] : 0;
    __syncthreads();
    part[t] += u;
    __syncthreads();
  }
  int run = boff[b] + ((t == 0) ? 0 : part[t - 1]);
#pragma unroll
  for (int i = 0; i < 4; ++i) {
    int idx = base + i;
    if (idx < nph) {
      offs[idx] = run;
      cursor[idx] = run;
      run += v[i];
    }
  }
}

__global__ __launch_bounds__(256)
void fill_kernel(const int* __restrict__ esrc, const int* __restrict__ edst,
                 int* __restrict__ cursor, int* __restrict__ csr, int ne) {
  int i = blockIdx.x * blockDim.x + threadIdx.x;
  int stride = gridDim.x * blockDim.x;
  for (int e = i; e < ne; e += stride) {
    int d = edst[e];
    int pos = atomicAdd(cursor + d, 1);
    csr[pos] = esrc[e];
  }
}

// ---------------- per-phase gather-reduce with 4-edge ILP -------------------
__global__ __launch_bounds__(256)
void agg_kernel(const unsigned short* __restrict__ h, const int* __restrict__ csr,
                const int* __restrict__ offs, unsigned short* __restrict__ agg,
                int nph) {
  const int grp = threadIdx.x >> 5;          // 0..7
  const int l   = threadIdx.x & 31;          // channel group: ch l*4..+3
  const int ph  = blockIdx.x * 8 + grp;
  if (ph >= nph) return;
  const int beg = offs[ph], end = offs[ph + 1];

  f32x4 a0 = (f32x4)0.f, a1 = (f32x4)0.f, a2 = (f32x4)0.f, a3 = (f32x4)0.f;
  int j = beg;
  for (; j + 4 <= end; j += 4) {
    int s0 = csr[j], s1 = csr[j + 1], s2 = csr[j + 2], s3 = csr[j + 3];
    ushort4 v0 = *(const ushort4*)(h + (size_t)s0 * 128 + l * 4);
    ushort4 v1 = *(const ushort4*)(h + (size_t)s1 * 128 + l * 4);
    ushort4 v2 = *(const ushort4*)(h + (size_t)s2 * 128 + l * 4);
    ushort4 v3 = *(const ushort4*)(h + (size_t)s3 * 128 + l * 4);
    a0[0] += bf2f(v0.x); a0[1] += bf2f(v0.y); a0[2] += bf2f(v0.z); a0[3] += bf2f(v0.w);
    a1[0] += bf2f(v1.x); a1[1] += bf2f(v1.y); a1[2] += bf2f(v1.z); a1[3] += bf2f(v1.w);
    a2[0] += bf2f(v2.x); a2[1] += bf2f(v2.y); a2[2] += bf2f(v2.z); a2[3] += bf2f(v2.w);
    a3[0] += bf2f(v3.x); a3[1] += bf2f(v3.y); a3[2] += bf2f(v3.z); a3[3] += bf2f(v3.w);
  }
  for (; j < end; ++j) {
    int s = csr[j];
    ushort4 v = *(const ushort4*)(h + (size_t)s * 128 + l * 4);
    a0[0] += bf2f(v.x); a0[1] += bf2f(v.y); a0[2] += bf2f(v.z); a0[3] += bf2f(v.w);
  }
  const float sc = 1.f / (float)max(end - beg, 1);
  ushort4 o;
  o.x = f2bf((a0[0] + a1[0] + a2[0] + a3[0]) * sc);
  o.y = f2bf((a0[1] + a1[1] + a2[1] + a3[1]) * sc);
  o.z = f2bf((a0[2] + a1[2] + a2[2] + a3[2]) * sc);
  o.w = f2bf((a0[3] + a1[3] + a2[3] + a3[3]) * sc);
  *(ushort4*)(agg + (size_t)ph * 128 + l * 4) = o;
}

// ---------------- phase MLP via MFMA (unchanged) ----------------------------
__global__ __launch_bounds__(256)
void phase_mlp_mfma(const unsigned short* __restrict__ aggb,
                    const unsigned short* __restrict__ w4t,
                    const unsigned short* __restrict__ w5t,
                    const float* __restrict__ b4, const float* __restrict__ b5,
                    const float* __restrict__ W6, const float* __restrict__ b6,
                    float* __restrict__ logits, int nph) {
  __shared__ unsigned short sH[64 * 128];
  float* sPart = (float*)sH;   // reused (after barrier) for head partials
  const int tid  = threadIdx.x;
  const int lane = tid & 63;
  const int w    = tid >> 6;
  const int rloc = lane & 15;
  const int g    = lane >> 4;
  const int r0w  = (w & 1) * 32;
  const int c0   = (w >> 1) * 64;
  const int rowBlk = blockIdx.x * 64;

  f32x4 acc[2][4];
  short8 Bf[4][4];

  // ---- layer 4: A from aggb global ----
#pragma unroll
  for (int ks = 0; ks < 4; ++ks)
#pragma unroll
    for (int cf = 0; cf < 4; ++cf)
      Bf[ks][cf] = *(const short8*)&w4t[(c0 + cf * 16 + rloc) * 128 + ks * 32 + g * 8];
#pragma unroll
  for (int rf = 0; rf < 2; ++rf)
#pragma unroll
    for (int cf = 0; cf < 4; ++cf) acc[rf][cf] = (f32x4)0.f;

  {
    const int row0 = rowBlk + r0w + rloc;
    const int row1 = row0 + 16;
#pragma unroll
    for (int ks = 0; ks < 4; ++ks) {
      short8 A0 = (short8)0, A1 = (short8)0;
      if (row0 < nph) A0 = *(const short8*)&aggb[(size_t)row0 * 128 + ks * 32 + g * 8];
      if (row1 < nph) A1 = *(const short8*)&aggb[(size_t)row1 * 128 + ks * 32 + g * 8];
#pragma unroll
      for (int cf = 0; cf < 4; ++cf) {
        acc[0][cf] = __builtin_amdgcn_mfma_f32_16x16x32_bf16(A0, Bf[ks][cf], acc[0][cf], 0, 0, 0);
        acc[1][cf] = __builtin_amdgcn_mfma_f32_16x16x32_bf16(A1, Bf[ks][cf], acc[1][cf], 0, 0, 0);
      }
    }
  }

  // epilogue layer 4 -> sH (swizzled)
  {
    float bv[4];
#pragma unroll
    for (int cf = 0; cf < 4; ++cf) bv[cf] = b4[c0 + cf * 16 + rloc];
#pragma unroll
    for (int rf = 0; rf < 2; ++rf)
#pragma unroll
      for (int cf = 0; cf < 4; ++cf)
#pragma unroll
        for (int i = 0; i < 4; ++i) {
          int row = r0w + rf * 16 + g * 4 + i;
          int col = c0 + cf * 16 + rloc;
          float v = fmaxf(acc[rf][cf][i] + bv[cf], 0.f);
          sH[row * 128 + (((col >> 3) ^ (row & 7)) << 3) + (col & 7)] = f2bf(v);
        }
  }
  __syncthreads();

  // ---- layer 5: A from sH ----
#pragma unroll
  for (int ks = 0; ks < 4; ++ks)
#pragma unroll
    for (int cf = 0; cf < 4; ++cf)
      Bf[ks][cf] = *(const short8*)&w5t[(c0 + cf * 16 + rloc) * 128 + ks * 32 + g * 8];
#pragma unroll
  for (int rf = 0; rf < 2; ++rf)
#pragma unroll
    for (int cf = 0; cf < 4; ++cf) acc[rf][cf] = (f32x4)0.f;

#pragma unroll
  for (int ks = 0; ks < 4; ++ks) {
    short8 A0, A1;
    {
      int row = r0w + rloc;
      int slot = (ks * 4 + g) ^ (row & 7);
      A0 = *(const short8*)&sH[row * 128 + slot * 8];
    }
    {
      int row = r0w + 16 + rloc;
      int slot = (ks * 4 + g) ^ (row & 7);
      A1 = *(const short8*)&sH[row * 128 + slot * 8];
    }
#pragma unroll
    for (int cf = 0; cf < 4; ++cf) {
      acc[0][cf] = __builtin_amdgcn_mfma_f32_16x16x32_bf16(A0, Bf[ks][cf], acc[0][cf], 0, 0, 0);
      acc[1][cf] = __builtin_amdgcn_mfma_f32_16x16x32_bf16(A1, Bf[ks][cf], acc[1][cf], 0, 0, 0);
    }
  }

  // ---- head: logits[r] = relu(acc + b5) . W6 + b6 ----
  float part8[2][4];
  {
    float bv[4], wv[4];
#pragma unroll
    for (int cf = 0; cf < 4; ++cf) {
      bv[cf] = b5[c0 + cf * 16 + rloc];
      wv[cf] = W6[c0 + cf * 16 + rloc];
    }
#pragma unroll
    for (int rf = 0; rf < 2; ++rf)
#pragma unroll
      for (int i = 0; i < 4; ++i) {
        float p = 0.f;
#pragma unroll
        for (int cf = 0; cf < 4; ++cf)
          p += fmaxf(acc[rf][cf][i] + bv[cf], 0.f) * wv[cf];
        part8[rf][i] = p;
      }
  }
#pragma unroll
  for (int m = 1; m < 16; m <<= 1) {
#pragma unroll
    for (int rf = 0; rf < 2; ++rf)
#pragma unroll
      for (int i = 0; i < 4; ++i)
        part8[rf][i] += __shfl_xor(part8[rf][i], m, 64);
  }
  __syncthreads();
  if (rloc == 0) {
#pragma unroll
    for (int rf = 0; rf < 2; ++rf)
#pragma unroll
      for (int i = 0; i < 4; ++i)
        sPart[(w >> 1) * 64 + r0w + rf * 16 + g * 4 + i] = part8[rf][i];
  }
  __syncthreads();
  if (tid < 64) {
    int gr = rowBlk + tid;
    if (gr < nph) logits[gr] = sPart[tid] + sPart[64 + tid] + b6[0];
  }
}

// ---------------------------------------------------------------------------
extern "C" void kernel_launch(void* const* d_in, const int* in_sizes, int n_in,
                              void* d_out, int out_size, void* d_ws, size_t ws_size,
                              hipStream_t stream) {
  const float* x  = (const float*)d_in[0];
  const float* W1 = (const float*)d_in[1];
  const float* b1 = (const float*)d_in[2];
  const float* W2 = (const float*)d_in[3];
  const float* b2 = (const float*)d_in[4];
  const float* W3 = (const float*)d_in[5];
  const float* b3 = (const float*)d_in[6];
  const float* W4 = (const float*)d_in[7];
  const float* b4 = (const float*)d_in[8];
  const float* W5 = (const float*)d_in[9];
  const float* b5 = (const float*)d_in[10];
  const float* W6 = (const float*)d_in[11];
  const float* b6 = (const float*)d_in[12];
  const int* esrc = (const int*)d_in[13];
  const int* edst = (const int*)d_in[14];

  const int nmov = in_sizes[0] / 16;
  const int ne   = in_sizes[13];
  const int nph  = out_size;

  char* ws = (char*)d_ws;
  size_t off = 0;
  auto take = [&](size_t bytes) {
    char* p = ws + off;
    off = (off + bytes + 255) & ~(size_t)255;
    return p;
  };
  unsigned short* hbuf = (unsigned short*)take((size_t)nmov * 128 * 2); // 128 MB
  int* csr             = (int*)take((size_t)ne * 4);                   //   4 MB
  int* cnt             = (int*)take((size_t)nph * 4);
  int* offs            = (int*)take(((size_t)nph + 1) * 4);
  int* cursor          = (int*)take((size_t)nph * 4);
  unsigned short* aggb = (unsigned short*)take((size_t)nph * 128 * 2); //  32 MB
  unsigned short* w1t  = (unsigned short*)take(128 * 32 * 2);
  unsigned short* w2t  = (unsigned short*)take(128 * 128 * 2);
  unsigned short* w3t  = (unsigned short*)take(128 * 128 * 2);
  unsigned short* w4t  = (unsigned short*)take(128 * 128 * 2);
  unsigned short* w5t  = (unsigned short*)take(128 * 128 * 2);
  const int nb = (nph + 1023) / 1024;            // <= 256 for nph <= 262144
  int* bsum            = (int*)take((size_t)nb * 4);
  int* boff            = (int*)take((size_t)nb * 4);
  if (off > ws_size) return;

  (void)hipMemsetAsync(cnt, 0, (size_t)nph * 4, stream);

  prep_weights<<<64, 256, 0, stream>>>(W1, W2, W3, W4, W5, w1t, w2t, w3t, w4t, w5t);

  int movBlocks = (nmov + 63) / 64;
  mov_mlp_mfma<<<movBlocks, 256, 0, stream>>>(x, w1t, w2t, w3t, b1, b2, b3, hbuf, nmov);

  hist_kernel<<<1024, 256, 0, stream>>>(edst, cnt, ne);
  scan_sum_kernel<<<nb, 256, 0, stream>>>(cnt, bsum, nph);
  scan_top_kernel<<<1, 256, 0, stream>>>(bsum, boff, offs + nph, nb);
  scan_fill_kernel<<<nb, 256, 0, stream>>>(cnt, boff, offs, cursor, nph);
  fill_kernel<<<1024, 256, 0, stream>>>(esrc, edst, cursor, csr, ne);

  int aggBlocks = (nph + 7) / 8;
  agg_kernel<<<aggBlocks, 256, 0, stream>>>(hbuf, csr, offs, aggb, nph);

  int phBlocks = (nph + 63) / 64;
  phase_mlp_mfma<<<phBlocks, 256, 0, stream>>>(aggb, w4t, w5t, b4, b5, W6, b6,
                                               (float*)d_out, nph);
}

// Round 14
// 370.481 us; speedup vs baseline: 1.3226x; 1.3226x over previous
//
#include <hip/hip_runtime.h>
#include <hip/hip_bf16.h>

// ---------------------------------------------------------------------------
// GraphActorNetwork: movement MLP (16->128->128->128) -> scatter-mean over
// edges -> phase MLP (128->128->128->1).
// Round 14: block-role fusion to overlap independent stages. mov variants
// r7-r13 bracket a ~165us floor (latency/L1-bound, pipes mostly idle), so
// stop rewriting mov; instead run fill's ~60us of atomic-bound work INSIDE
// the mov launch (blocks 0..1023 = fill, rest = mov tiles; independent
// work, uniform per-block branch). prep fused with hist likewise.
// DAG: memset -> [prep|hist] -> scans -> [fill|mov] -> agg -> phase.
// mov body = round-10 proven config (4 waves, 64-row tile, VGPR 60, 168us).
// agg (4-edge ILP), scans, phase MLP unchanged. r11 baseline: 378us.
// ---------------------------------------------------------------------------

typedef __attribute__((ext_vector_type(8))) short short8;
typedef __attribute__((ext_vector_type(4))) float f32x4;

union U8 { short8 s8; unsigned int u[4]; };

__device__ __forceinline__ float bf2f(unsigned short u) {
  return __uint_as_float(((unsigned int)u) << 16);
}
__device__ __forceinline__ unsigned short f2bf(float f) {
  unsigned int u = __float_as_uint(f);
  u = (u + 0x7fffu + ((u >> 16) & 1u)) >> 16;   // RNE
  return (unsigned short)u;
}
__device__ __forceinline__ unsigned int pk2(float a, float b) {
  __hip_bfloat162 h = __float22bfloat162_rn(make_float2(a, b));
  unsigned int u;
  __builtin_memcpy(&u, &h, 4);
  return u;
}

// ---------------- fused: prep (blocks 0..63) + hist (blocks 64..) -----------
__global__ __launch_bounds__(256)
void prep_hist_kernel(const float* __restrict__ W1, const float* __restrict__ W2,
                      const float* __restrict__ W3, const float* __restrict__ W4,
                      const float* __restrict__ W5,
                      unsigned short* __restrict__ w1t, unsigned short* __restrict__ w2t,
                      unsigned short* __restrict__ w3t, unsigned short* __restrict__ w4t,
                      unsigned short* __restrict__ w5t,
                      const int* __restrict__ edst, int* __restrict__ cnt, int ne,
                      int histBlocks) {
  const int bid = blockIdx.x;
  if (bid < 64) {
    int t = bid * 256 + threadIdx.x;
    const int stride = 64 * 256;
    if (t < 128 * 32) {
      int c = t >> 5, k = t & 31;
      w1t[t] = (k < 16) ? f2bf(W1[k * 128 + c]) : 0;
    }
    for (int i = t; i < 128 * 128; i += stride) {
      int c = i >> 7, k = i & 127;
      w2t[i] = f2bf(W2[k * 128 + c]);
      w3t[i] = f2bf(W3[k * 128 + c]);
      w4t[i] = f2bf(W4[k * 128 + c]);
      w5t[i] = f2bf(W5[k * 128 + c]);
    }
  } else {
    int i = (bid - 64) * 256 + threadIdx.x;
    int stride = histBlocks * 256;
    for (int e = i; e < ne; e += stride) atomicAdd(cnt + edst[e], 1);
  }
}

// hierarchical scan: 1024 elems per block. s1: per-block sums.
__global__ __launch_bounds__(256)
void scan_sum_kernel(const int* __restrict__ cnt, int* __restrict__ bsum, int nph) {
  __shared__ int red[256];
  const int b = blockIdx.x, t = threadIdx.x;
  const int base = b * 1024 + t * 4;
  int s = 0;
#pragma unroll
  for (int i = 0; i < 4; ++i) {
    int idx = base + i;
    if (idx < nph) s += cnt[idx];
  }
  red[t] = s;
  __syncthreads();
  for (int d = 128; d > 0; d >>= 1) {
    if (t < d) red[t] += red[t + d];
    __syncthreads();
  }
  if (t == 0) bsum[b] = red[0];
}

// s2: exclusive scan of bsum[nb] (nb <= 256) -> boff; total -> *offs_end.
__global__ __launch_bounds__(256)
void scan_top_kernel(const int* __restrict__ bsum, int* __restrict__ boff,
                     int* __restrict__ offs_end, int nb) {
  __shared__ int part[256];
  const int t = threadIdx.x;
  part[t] = (t < nb) ? bsum[t] : 0;
  __syncthreads();
  for (int d = 1; d < 256; d <<= 1) {
    int v = (t >= d) ? part[t - d] : 0;
    __syncthreads();
    part[t] += v;
    __syncthreads();
  }
  if (t < nb) boff[t] = (t == 0) ? 0 : part[t - 1];
  if (t == 255) *offs_end = part[255];
}

// s3: per-block exclusive scan + base offset -> offs, cursor.
__global__ __launch_bounds__(256)
void scan_fill_kernel(const int* __restrict__ cnt, const int* __restrict__ boff,
                      int* __restrict__ offs, int* __restrict__ cursor, int nph) {
  __shared__ int part[256];
  const int b = blockIdx.x, t = threadIdx.x;
  const int base = b * 1024 + t * 4;
  int v[4];
  int s = 0;
#pragma unroll
  for (int i = 0; i < 4; ++i) {
    int idx = base + i;
    v[i] = (idx < nph) ? cnt[idx] : 0;
    s += v[i];
  }
  part[t] = s;
  __syncthreads();
  for (int d = 1; d < 256; d <<= 1) {
    int u = (t >= d) ? part[t - d] : 0;
    __syncthreads();
    part[t] += u;
    __syncthreads();
  }
  int run = boff[b] + ((t == 0) ? 0 : part[t - 1]);
#pragma unroll
  for (int i = 0; i < 4; ++i) {
    int idx = base + i;
    if (idx < nph) {
      offs[idx] = run;
      cursor[idx] = run;
      run += v[i];
    }
  }
}

// ---------------- fused: fill (blocks 0..fillBlocks-1) + mov (rest) ---------
// fill: CSR fill via cursor atomics (needs scan done; atomic/latency-bound,
// no MFMA). mov: round-10 proven MFMA body (4 waves, 64-row tile, swapped
// operands D^T = mfma(Wfrag, actfrag), XOR-swizzled 16KB LDS, bias folded).
// Independent work -> concurrent execution fills mov's idle issue slots.
__global__ __launch_bounds__(256)
void fill_mov_kernel(const int* __restrict__ esrc, const int* __restrict__ edst,
                     int* __restrict__ cursor, int* __restrict__ csr, int ne,
                     int fillBlocks,
                     const float* __restrict__ x,
                     const unsigned short* __restrict__ w1t,
                     const unsigned short* __restrict__ w2t,
                     const unsigned short* __restrict__ w3t,
                     const float* __restrict__ b1, const float* __restrict__ b2,
                     const float* __restrict__ b3,
                     unsigned short* __restrict__ hout, int nrows) {
  __shared__ unsigned short sH[64 * 128];   // 16 KB (mov path only)
  const int bid = blockIdx.x;

  if (bid < fillBlocks) {
    int i = bid * 256 + threadIdx.x;
    int stride = fillBlocks * 256;
    for (int e = i; e < ne; e += stride) {
      int d = edst[e];
      int pos = atomicAdd(cursor + d, 1);
      csr[pos] = esrc[e];
    }
    return;
  }

  // ---------------- mov path ----------------
  const int movBid = bid - fillBlocks;
  const int tid  = threadIdx.x;
  const int lane = tid & 63;
  const int w    = tid >> 6;
  const int li   = lane & 15;     // sample-in-frag
  const int g    = lane >> 4;     // k-group / channel sub-block
  const int r0w  = (w & 1) * 32;  // wave row base
  const int c0   = (w >> 1) * 64; // wave col base
  const int rowBlk = movBid * 64;

  f32x4 acc[2][4];   // [rf][cf]
  short8 Bf[4][4];   // [ks][cf] hoisted weight frags

  // ---- layer 1: act from global x (K=32, k 16..31 zero) ----
#pragma unroll
  for (int cf = 0; cf < 4; ++cf) {
    float4 b4 = *(const float4*)&b1[c0 + cf * 16 + g * 4];
#pragma unroll
    for (int rf = 0; rf < 2; ++rf) {
      acc[rf][cf][0] = b4.x; acc[rf][cf][1] = b4.y;
      acc[rf][cf][2] = b4.z; acc[rf][cf][3] = b4.w;
    }
  }
  {
    short8 Ax[2];
#pragma unroll
    for (int rf = 0; rf < 2; ++rf) {
      U8 a; a.s8 = (short8)0;
      int row = rowBlk + r0w + rf * 16 + li;
      if (g < 2 && row < nrows) {
        const float* xp = x + (size_t)row * 16 + g * 8;
        float4 u0 = *(const float4*)xp;
        float4 u1 = *(const float4*)(xp + 4);
        a.u[0] = pk2(u0.x, u0.y); a.u[1] = pk2(u0.z, u0.w);
        a.u[2] = pk2(u1.x, u1.y); a.u[3] = pk2(u1.z, u1.w);
      }
      Ax[rf] = a.s8;
    }
    short8 B1[4];
#pragma unroll
    for (int cf = 0; cf < 4; ++cf)
      B1[cf] = *(const short8*)&w1t[(c0 + cf * 16 + li) * 32 + g * 8];
#pragma unroll
    for (int rf = 0; rf < 2; ++rf)
#pragma unroll
      for (int cf = 0; cf < 4; ++cf)
        acc[rf][cf] = __builtin_amdgcn_mfma_f32_16x16x32_bf16(B1[cf], Ax[rf], acc[rf][cf], 0, 0, 0);
  }

  // epilogue layer 1 -> sH (relu; bias already in acc); 8B contiguous writes
#pragma unroll
  for (int rf = 0; rf < 2; ++rf) {
    int s = r0w + rf * 16 + li;
    unsigned short* dst = &sH[s * 128 + (g & 1) * 4];
    int sx = s & 7;
#pragma unroll
    for (int cf = 0; cf < 4; ++cf) {
      int gi = (c0 >> 3) + cf * 2 + (g >> 1);
      int slot = gi ^ sx;
      uint2 u;
      u.x = pk2(fmaxf(acc[rf][cf][0], 0.f), fmaxf(acc[rf][cf][1], 0.f));
      u.y = pk2(fmaxf(acc[rf][cf][2], 0.f), fmaxf(acc[rf][cf][3], 0.f));
      *(uint2*)(dst + slot * 8) = u;
    }
  }
  __syncthreads();

  // ---- layers 2 and 3 ----
  const unsigned short* wts[2] = { w2t, w3t };
  const float* bs[2] = { b2, b3 };
#pragma unroll 1
  for (int layer = 0; layer < 2; ++layer) {
    const unsigned short* wt = wts[layer];
    const float* bb = bs[layer];
#pragma unroll
    for (int ks = 0; ks < 4; ++ks)
#pragma unroll
      for (int cf = 0; cf < 4; ++cf)
        Bf[ks][cf] = *(const short8*)&wt[(c0 + cf * 16 + li) * 128 + ks * 32 + g * 8];

#pragma unroll
    for (int cf = 0; cf < 4; ++cf) {
      float4 b4 = *(const float4*)&bb[c0 + cf * 16 + g * 4];
#pragma unroll
      for (int rf = 0; rf < 2; ++rf) {
        acc[rf][cf][0] = b4.x; acc[rf][cf][1] = b4.y;
        acc[rf][cf][2] = b4.z; acc[rf][cf][3] = b4.w;
      }
    }

#pragma unroll
    for (int ks = 0; ks < 4; ++ks) {
      short8 Ar[2];
#pragma unroll
      for (int rf = 0; rf < 2; ++rf) {
        int s = r0w + rf * 16 + li;
        int slot = (ks * 4 + g) ^ (s & 7);
        Ar[rf] = *(const short8*)&sH[s * 128 + slot * 8];
      }
#pragma unroll
      for (int rf = 0; rf < 2; ++rf)
#pragma unroll
        for (int cf = 0; cf < 4; ++cf)
          acc[rf][cf] = __builtin_amdgcn_mfma_f32_16x16x32_bf16(Bf[ks][cf], Ar[rf], acc[rf][cf], 0, 0, 0);
    }
    __syncthreads();   // all sH reads done before overwrite

#pragma unroll
    for (int rf = 0; rf < 2; ++rf) {
      int s = r0w + rf * 16 + li;
      unsigned short* dst = &sH[s * 128 + (g & 1) * 4];
      int sx = s & 7;
#pragma unroll
      for (int cf = 0; cf < 4; ++cf) {
        int gi = (c0 >> 3) + cf * 2 + (g >> 1);
        int slot = gi ^ sx;
        uint2 u;
        u.x = pk2(fmaxf(acc[rf][cf][0], 0.f), fmaxf(acc[rf][cf][1], 0.f));
        u.y = pk2(fmaxf(acc[rf][cf][2], 0.f), fmaxf(acc[rf][cf][3], 0.f));
        *(uint2*)(dst + slot * 8) = u;
      }
    }
    __syncthreads();
  }

  // ---- coalesced copy-out: sH -> hout (16B/lane x 4) ----
  {
    int r = tid >> 2;             // 0..63
    int q = tid & 3;              // granule quarter
    int grow = rowBlk + r;
    if (grow < nrows) {
#pragma unroll
      for (int i = 0; i < 4; ++i) {
        int gi = q * 4 + i;       // logical granule (8 ch)
        int slot = gi ^ (r & 7);
        short8 v = *(const short8*)&sH[r * 128 + slot * 8];
        *(short8*)(hout + (size_t)grow * 128 + gi * 8) = v;
      }
    }
  }
}

// ---------------- per-phase gather-reduce with 4-edge ILP -------------------
__global__ __launch_bounds__(256)
void agg_kernel(const unsigned short* __restrict__ h, const int* __restrict__ csr,
                const int* __restrict__ offs, unsigned short* __restrict__ agg,
                int nph) {
  const int grp = threadIdx.x >> 5;          // 0..7
  const int l   = threadIdx.x & 31;          // channel group: ch l*4..+3
  const int ph  = blockIdx.x * 8 + grp;
  if (ph >= nph) return;
  const int beg = offs[ph], end = offs[ph + 1];

  f32x4 a0 = (f32x4)0.f, a1 = (f32x4)0.f, a2 = (f32x4)0.f, a3 = (f32x4)0.f;
  int j = beg;
  for (; j + 4 <= end; j += 4) {
    int s0 = csr[j], s1 = csr[j + 1], s2 = csr[j + 2], s3 = csr[j + 3];
    ushort4 v0 = *(const ushort4*)(h + (size_t)s0 * 128 + l * 4);
    ushort4 v1 = *(const ushort4*)(h + (size_t)s1 * 128 + l * 4);
    ushort4 v2 = *(const ushort4*)(h + (size_t)s2 * 128 + l * 4);
    ushort4 v3 = *(const ushort4*)(h + (size_t)s3 * 128 + l * 4);
    a0[0] += bf2f(v0.x); a0[1] += bf2f(v0.y); a0[2] += bf2f(v0.z); a0[3] += bf2f(v0.w);
    a1[0] += bf2f(v1.x); a1[1] += bf2f(v1.y); a1[2] += bf2f(v1.z); a1[3] += bf2f(v1.w);
    a2[0] += bf2f(v2.x); a2[1] += bf2f(v2.y); a2[2] += bf2f(v2.z); a2[3] += bf2f(v2.w);
    a3[0] += bf2f(v3.x); a3[1] += bf2f(v3.y); a3[2] += bf2f(v3.z); a3[3] += bf2f(v3.w);
  }
  for (; j < end; ++j) {
    int s = csr[j];
    ushort4 v = *(const ushort4*)(h + (size_t)s * 128 + l * 4);
    a0[0] += bf2f(v.x); a0[1] += bf2f(v.y); a0[2] += bf2f(v.z); a0[3] += bf2f(v.w);
  }
  const float sc = 1.f / (float)max(end - beg, 1);
  ushort4 o;
  o.x = f2bf((a0[0] + a1[0] + a2[0] + a3[0]) * sc);
  o.y = f2bf((a0[1] + a1[1] + a2[1] + a3[1]) * sc);
  o.z = f2bf((a0[2] + a1[2] + a2[2] + a3[2]) * sc);
  o.w = f2bf((a0[3] + a1[3] + a2[3] + a3[3]) * sc);
  *(ushort4*)(agg + (size_t)ph * 128 + l * 4) = o;
}

// ---------------- phase MLP via MFMA (unchanged) ----------------------------
__global__ __launch_bounds__(256)
void phase_mlp_mfma(const unsigned short* __restrict__ aggb,
                    const unsigned short* __restrict__ w4t,
                    const unsigned short* __restrict__ w5t,
                    const float* __restrict__ b4, const float* __restrict__ b5,
                    const float* __restrict__ W6, const float* __restrict__ b6,
                    float* __restrict__ logits, int nph) {
  __shared__ unsigned short sH[64 * 128];
  float* sPart = (float*)sH;   // reused (after barrier) for head partials
  const int tid  = threadIdx.x;
  const int lane = tid & 63;
  const int w    = tid >> 6;
  const int rloc = lane & 15;
  const int g    = lane >> 4;
  const int r0w  = (w & 1) * 32;
  const int c0   = (w >> 1) * 64;
  const int rowBlk = blockIdx.x * 64;

  f32x4 acc[2][4];
  short8 Bf[4][4];

  // ---- layer 4: A from aggb global ----
#pragma unroll
  for (int ks = 0; ks < 4; ++ks)
#pragma unroll
    for (int cf = 0; cf < 4; ++cf)
      Bf[ks][cf] = *(const short8*)&w4t[(c0 + cf * 16 + rloc) * 128 + ks * 32 + g * 8];
#pragma unroll
  for (int rf = 0; rf < 2; ++rf)
#pragma unroll
    for (int cf = 0; cf < 4; ++cf) acc[rf][cf] = (f32x4)0.f;

  {
    const int row0 = rowBlk + r0w + rloc;
    const int row1 = row0 + 16;
#pragma unroll
    for (int ks = 0; ks < 4; ++ks) {
      short8 A0 = (short8)0, A1 = (short8)0;
      if (row0 < nph) A0 = *(const short8*)&aggb[(size_t)row0 * 128 + ks * 32 + g * 8];
      if (row1 < nph) A1 = *(const short8*)&aggb[(size_t)row1 * 128 + ks * 32 + g * 8];
#pragma unroll
      for (int cf = 0; cf < 4; ++cf) {
        acc[0][cf] = __builtin_amdgcn_mfma_f32_16x16x32_bf16(A0, Bf[ks][cf], acc[0][cf], 0, 0, 0);
        acc[1][cf] = __builtin_amdgcn_mfma_f32_16x16x32_bf16(A1, Bf[ks][cf], acc[1][cf], 0, 0, 0);
      }
    }
  }

  // epilogue layer 4 -> sH (swizzled)
  {
    float bv[4];
#pragma unroll
    for (int cf = 0; cf < 4; ++cf) bv[cf] = b4[c0 + cf * 16 + rloc];
#pragma unroll
    for (int rf = 0; rf < 2; ++rf)
#pragma unroll
      for (int cf = 0; cf < 4; ++cf)
#pragma unroll
        for (int i = 0; i < 4; ++i) {
          int row = r0w + rf * 16 + g * 4 + i;
          int col = c0 + cf * 16 + rloc;
          float v = fmaxf(acc[rf][cf][i] + bv[cf], 0.f);
          sH[row * 128 + (((col >> 3) ^ (row & 7)) << 3) + (col & 7)] = f2bf(v);
        }
  }
  __syncthreads();

  // ---- layer 5: A from sH ----
#pragma unroll
  for (int ks = 0; ks < 4; ++ks)
#pragma unroll
    for (int cf = 0; cf < 4; ++cf)
      Bf[ks][cf] = *(const short8*)&w5t[(c0 + cf * 16 + rloc) * 128 + ks * 32 + g * 8];
#pragma unroll
  for (int rf = 0; rf < 2; ++rf)
#pragma unroll
    for (int cf = 0; cf < 4; ++cf) acc[rf][cf] = (f32x4)0.f;

#pragma unroll
  for (int ks = 0; ks < 4; ++ks) {
    short8 A0, A1;
    {
      int row = r0w + rloc;
      int slot = (ks * 4 + g) ^ (row & 7);
      A0 = *(const short8*)&sH[row * 128 + slot * 8];
    }
    {
      int row = r0w + 16 + rloc;
      int slot = (ks * 4 + g) ^ (row & 7);
      A1 = *(const short8*)&sH[row * 128 + slot * 8];
    }
#pragma unroll
    for (int cf = 0; cf < 4; ++cf) {
      acc[0][cf] = __builtin_amdgcn_mfma_f32_16x16x32_bf16(A0, Bf[ks][cf], acc[0][cf], 0, 0, 0);
      acc[1][cf] = __builtin_amdgcn_mfma_f32_16x16x32_bf16(A1, Bf[ks][cf], acc[1][cf], 0, 0, 0);
    }
  }

  // ---- head: logits[r] = relu(acc + b5) . W6 + b6 ----
  float part8[2][4];
  {
    float bv[4], wv[4];
#pragma unroll
    for (int cf = 0; cf < 4; ++cf) {
      bv[cf] = b5[c0 + cf * 16 + rloc];
      wv[cf] = W6[c0 + cf * 16 + rloc];
    }
#pragma unroll
    for (int rf = 0; rf < 2; ++rf)
#pragma unroll
      for (int i = 0; i < 4; ++i) {
        float p = 0.f;
#pragma unroll
        for (int cf = 0; cf < 4; ++cf)
          p += fmaxf(acc[rf][cf][i] + bv[cf], 0.f) * wv[cf];
        part8[rf][i] = p;
      }
  }
#pragma unroll
  for (int m = 1; m < 16; m <<= 1) {
#pragma unroll
    for (int rf = 0; rf < 2; ++rf)
#pragma unroll
      for (int i = 0; i < 4; ++i)
        part8[rf][i] += __shfl_xor(part8[rf][i], m, 64);
  }
  __syncthreads();
  if (rloc == 0) {
#pragma unroll
    for (int rf = 0; rf < 2; ++rf)
#pragma unroll
      for (int i = 0; i < 4; ++i)
        sPart[(w >> 1) * 64 + r0w + rf * 16 + g * 4 + i] = part8[rf][i];
  }
  __syncthreads();
  if (tid < 64) {
    int gr = rowBlk + tid;
    if (gr < nph) logits[gr] = sPart[tid] + sPart[64 + tid] + b6[0];
  }
}

// ---------------------------------------------------------------------------
extern "C" void kernel_launch(void* const* d_in, const int* in_sizes, int n_in,
                              void* d_out, int out_size, void* d_ws, size_t ws_size,
                              hipStream_t stream) {
  const float* x  = (const float*)d_in[0];
  const float* W1 = (const float*)d_in[1];
  const float* b1 = (const float*)d_in[2];
  const float* W2 = (const float*)d_in[3];
  const float* b2 = (const float*)d_in[4];
  const float* W3 = (const float*)d_in[5];
  const float* b3 = (const float*)d_in[6];
  const float* W4 = (const float*)d_in[7];
  const float* b4 = (const float*)d_in[8];
  const float* W5 = (const float*)d_in[9];
  const float* b5 = (const float*)d_in[10];
  const float* W6 = (const float*)d_in[11];
  const float* b6 = (const float*)d_in[12];
  const int* esrc = (const int*)d_in[13];
  const int* edst = (const int*)d_in[14];

  const int nmov = in_sizes[0] / 16;
  const int ne   = in_sizes[13];
  const int nph  = out_size;

  char* ws = (char*)d_ws;
  size_t off = 0;
  auto take = [&](size_t bytes) {
    char* p = ws + off;
    off = (off + bytes + 255) & ~(size_t)255;
    return p;
  };
  unsigned short* hbuf = (unsigned short*)take((size_t)nmov * 128 * 2); // 128 MB
  int* csr             = (int*)take((size_t)ne * 4);                   //   4 MB
  int* cnt             = (int*)take((size_t)nph * 4);
  int* offs            = (int*)take(((size_t)nph + 1) * 4);
  int* cursor          = (int*)take((size_t)nph * 4);
  unsigned short* aggb = (unsigned short*)take((size_t)nph * 128 * 2); //  32 MB
  unsigned short* w1t  = (unsigned short*)take(128 * 32 * 2);
  unsigned short* w2t  = (unsigned short*)take(128 * 128 * 2);
  unsigned short* w3t  = (unsigned short*)take(128 * 128 * 2);
  unsigned short* w4t  = (unsigned short*)take(128 * 128 * 2);
  unsigned short* w5t  = (unsigned short*)take(128 * 128 * 2);
  const int nb = (nph + 1023) / 1024;            // <= 256 for nph <= 262144
  int* bsum            = (int*)take((size_t)nb * 4);
  int* boff            = (int*)take((size_t)nb * 4);
  if (off > ws_size) return;

  (void)hipMemsetAsync(cnt, 0, (size_t)nph * 4, stream);

  const int histBlocks = 1024;
  prep_hist_kernel<<<64 + histBlocks, 256, 0, stream>>>(
      W1, W2, W3, W4, W5, w1t, w2t, w3t, w4t, w5t, edst, cnt, ne, histBlocks);

  scan_sum_kernel<<<nb, 256, 0, stream>>>(cnt, bsum, nph);
  scan_top_kernel<<<1, 256, 0, stream>>>(bsum, boff, offs + nph, nb);
  scan_fill_kernel<<<nb, 256, 0, stream>>>(cnt, boff, offs, cursor, nph);

  const int fillBlocks = 1024;
  const int movBlocks = (nmov + 63) / 64;
  fill_mov_kernel<<<fillBlocks + movBlocks, 256, 0, stream>>>(
      esrc, edst, cursor, csr, ne, fillBlocks,
      x, w1t, w2t, w3t, b1, b2, b3, hbuf, nmov);

  int aggBlocks = (nph + 7) / 8;
  agg_kernel<<<aggBlocks, 256, 0, stream>>>(hbuf, csr, offs, aggb, nph);

  int phBlocks = (nph + 63) / 64;
  phase_mlp_mfma<<<phBlocks, 256, 0, stream>>>(aggb, w4t, w5t, b4, b5, W6, b6,
                                               (float*)d_out, nph);
}

// Round 15
// 293.418 us; speedup vs baseline: 1.6700x; 1.2626x over previous
//
#include <hip/hip_runtime.h>
#include <hip/hip_bf16.h>

// ---------------------------------------------------------------------------
// GraphActorNetwork: movement MLP (16->128->128->128) -> scatter-mean over
// edges -> phase MLP (128->128->128->1).
// Round 15: INTERLEAVED block-role fusion. r14's [fill..., mov...] grid ran
// serially (blocks dispatch in order; fill_mov=244us ~= fill+mov serial).
// Fix: interleave roles (every k-th block = latency-bound role) so both
// populations are co-resident; and split mov rows across two fused kernels:
//   memset -> prep -> [movA || hist] -> scans -> [movB || fill] -> agg -> phase
// mov body = r10 proven config (4 waves, 64-row tile, swapped-operand D^T,
// XOR-swizzled 16KB LDS, VGPR ~60, 165us standalone).
// agg (4-edge ILP), scans, phase MLP unchanged. r14: 370us, absmax 2.9e-3.
// ---------------------------------------------------------------------------

typedef __attribute__((ext_vector_type(8))) short short8;
typedef __attribute__((ext_vector_type(4))) float f32x4;

union U8 { short8 s8; unsigned int u[4]; };

__device__ __forceinline__ float bf2f(unsigned short u) {
  return __uint_as_float(((unsigned int)u) << 16);
}
__device__ __forceinline__ unsigned short f2bf(float f) {
  unsigned int u = __float_as_uint(f);
  u = (u + 0x7fffu + ((u >> 16) & 1u)) >> 16;   // RNE
  return (unsigned short)u;
}
__device__ __forceinline__ unsigned int pk2(float a, float b) {
  __hip_bfloat162 h = __float22bfloat162_rn(make_float2(a, b));
  unsigned int u;
  __builtin_memcpy(&u, &h, 4);
  return u;
}

// ---------------- weight prep: f32 -> bf16 transposed (tiny, ~10us) ---------
__global__ __launch_bounds__(256)
void prep_weights(const float* __restrict__ W1, const float* __restrict__ W2,
                  const float* __restrict__ W3, const float* __restrict__ W4,
                  const float* __restrict__ W5,
                  unsigned short* __restrict__ w1t, unsigned short* __restrict__ w2t,
                  unsigned short* __restrict__ w3t, unsigned short* __restrict__ w4t,
                  unsigned short* __restrict__ w5t) {
  int t = blockIdx.x * blockDim.x + threadIdx.x;
  int stride = gridDim.x * blockDim.x;
  if (t < 128 * 32) {
    int c = t >> 5, k = t & 31;
    w1t[t] = (k < 16) ? f2bf(W1[k * 128 + c]) : 0;
  }
  for (int i = t; i < 128 * 128; i += stride) {
    int c = i >> 7, k = i & 127;
    w2t[i] = f2bf(W2[k * 128 + c]);
    w3t[i] = f2bf(W3[k * 128 + c]);
    w4t[i] = f2bf(W4[k * 128 + c]);
    w5t[i] = f2bf(W5[k * 128 + c]);
  }
}

// ---------------- mov tile body (r10 proven; called from fused kernels) -----
__device__ __forceinline__
void mov_tile(int rowBlk, unsigned short* sH,
              const float* __restrict__ x,
              const unsigned short* __restrict__ w1t,
              const unsigned short* __restrict__ w2t,
              const unsigned short* __restrict__ w3t,
              const float* __restrict__ b1, const float* __restrict__ b2,
              const float* __restrict__ b3,
              unsigned short* __restrict__ hout, int nrows) {
  const int tid  = threadIdx.x;
  const int lane = tid & 63;
  const int w    = tid >> 6;
  const int li   = lane & 15;     // sample-in-frag
  const int g    = lane >> 4;     // k-group / channel sub-block
  const int r0w  = (w & 1) * 32;  // wave row base
  const int c0   = (w >> 1) * 64; // wave col base

  f32x4 acc[2][4];   // [rf][cf]
  short8 Bf[4][4];   // [ks][cf] hoisted weight frags

  // ---- layer 1: act from global x (K=32, k 16..31 zero) ----
#pragma unroll
  for (int cf = 0; cf < 4; ++cf) {
    float4 b4 = *(const float4*)&b1[c0 + cf * 16 + g * 4];
#pragma unroll
    for (int rf = 0; rf < 2; ++rf) {
      acc[rf][cf][0] = b4.x; acc[rf][cf][1] = b4.y;
      acc[rf][cf][2] = b4.z; acc[rf][cf][3] = b4.w;
    }
  }
  {
    short8 Ax[2];
#pragma unroll
    for (int rf = 0; rf < 2; ++rf) {
      U8 a; a.s8 = (short8)0;
      int row = rowBlk + r0w + rf * 16 + li;
      if (g < 2 && row < nrows) {
        const float* xp = x + (size_t)row * 16 + g * 8;
        float4 u0 = *(const float4*)xp;
        float4 u1 = *(const float4*)(xp + 4);
        a.u[0] = pk2(u0.x, u0.y); a.u[1] = pk2(u0.z, u0.w);
        a.u[2] = pk2(u1.x, u1.y); a.u[3] = pk2(u1.z, u1.w);
      }
      Ax[rf] = a.s8;
    }
    short8 B1[4];
#pragma unroll
    for (int cf = 0; cf < 4; ++cf)
      B1[cf] = *(const short8*)&w1t[(c0 + cf * 16 + li) * 32 + g * 8];
#pragma unroll
    for (int rf = 0; rf < 2; ++rf)
#pragma unroll
      for (int cf = 0; cf < 4; ++cf)
        acc[rf][cf] = __builtin_amdgcn_mfma_f32_16x16x32_bf16(B1[cf], Ax[rf], acc[rf][cf], 0, 0, 0);
  }

  // epilogue layer 1 -> sH
#pragma unroll
  for (int rf = 0; rf < 2; ++rf) {
    int s = r0w + rf * 16 + li;
    unsigned short* dst = &sH[s * 128 + (g & 1) * 4];
    int sx = s & 7;
#pragma unroll
    for (int cf = 0; cf < 4; ++cf) {
      int gi = (c0 >> 3) + cf * 2 + (g >> 1);
      int slot = gi ^ sx;
      uint2 u;
      u.x = pk2(fmaxf(acc[rf][cf][0], 0.f), fmaxf(acc[rf][cf][1], 0.f));
      u.y = pk2(fmaxf(acc[rf][cf][2], 0.f), fmaxf(acc[rf][cf][3], 0.f));
      *(uint2*)(dst + slot * 8) = u;
    }
  }
  __syncthreads();

  // ---- layers 2 and 3 ----
  const unsigned short* wts[2] = { w2t, w3t };
  const float* bs[2] = { b2, b3 };
#pragma unroll 1
  for (int layer = 0; layer < 2; ++layer) {
    const unsigned short* wt = wts[layer];
    const float* bb = bs[layer];
#pragma unroll
    for (int ks = 0; ks < 4; ++ks)
#pragma unroll
      for (int cf = 0; cf < 4; ++cf)
        Bf[ks][cf] = *(const short8*)&wt[(c0 + cf * 16 + li) * 128 + ks * 32 + g * 8];

#pragma unroll
    for (int cf = 0; cf < 4; ++cf) {
      float4 b4 = *(const float4*)&bb[c0 + cf * 16 + g * 4];
#pragma unroll
      for (int rf = 0; rf < 2; ++rf) {
        acc[rf][cf][0] = b4.x; acc[rf][cf][1] = b4.y;
        acc[rf][cf][2] = b4.z; acc[rf][cf][3] = b4.w;
      }
    }

#pragma unroll
    for (int ks = 0; ks < 4; ++ks) {
      short8 Ar[2];
#pragma unroll
      for (int rf = 0; rf < 2; ++rf) {
        int s = r0w + rf * 16 + li;
        int slot = (ks * 4 + g) ^ (s & 7);
        Ar[rf] = *(const short8*)&sH[s * 128 + slot * 8];
      }
#pragma unroll
      for (int rf = 0; rf < 2; ++rf)
#pragma unroll
        for (int cf = 0; cf < 4; ++cf)
          acc[rf][cf] = __builtin_amdgcn_mfma_f32_16x16x32_bf16(Bf[ks][cf], Ar[rf], acc[rf][cf], 0, 0, 0);
    }
    __syncthreads();

#pragma unroll
    for (int rf = 0; rf < 2; ++rf) {
      int s = r0w + rf * 16 + li;
      unsigned short* dst = &sH[s * 128 + (g & 1) * 4];
      int sx = s & 7;
#pragma unroll
      for (int cf = 0; cf < 4; ++cf) {
        int gi = (c0 >> 3) + cf * 2 + (g >> 1);
        int slot = gi ^ sx;
        uint2 u;
        u.x = pk2(fmaxf(acc[rf][cf][0], 0.f), fmaxf(acc[rf][cf][1], 0.f));
        u.y = pk2(fmaxf(acc[rf][cf][2], 0.f), fmaxf(acc[rf][cf][3], 0.f));
        *(uint2*)(dst + slot * 8) = u;
      }
    }
    __syncthreads();
  }

  // ---- coalesced copy-out ----
  {
    int r = tid >> 2;
    int q = tid & 3;
    int grow = rowBlk + r;
    if (grow < nrows) {
#pragma unroll
      for (int i = 0; i < 4; ++i) {
        int gi = q * 4 + i;
        int slot = gi ^ (r & 7);
        short8 v = *(const short8*)&sH[r * 128 + slot * 8];
        *(short8*)(hout + (size_t)grow * 128 + gi * 8) = v;
      }
    }
  }
}

// role map: every k-th block (b%k==k-1, b/k<otherB) takes the "other" role.
// movIdx = b - (#other blocks at positions <= b) -- bijective.
__device__ __forceinline__ bool role_other(int b, int k, int otherB, int* oIdx, int* mIdx) {
  bool other = ((b % k) == (k - 1)) && ((b / k) < otherB);
  *oIdx = b / k;
  int before = min((b + 1) / k, otherB);
  *mIdx = b - before;
  return other;
}

// ---------------- K1: movA (rows 0..movA*64) interleaved with hist ----------
__global__ __launch_bounds__(256)
void mov_hist_kernel(const float* __restrict__ x,
                     const unsigned short* __restrict__ w1t,
                     const unsigned short* __restrict__ w2t,
                     const unsigned short* __restrict__ w3t,
                     const float* __restrict__ b1, const float* __restrict__ b2,
                     const float* __restrict__ b3,
                     unsigned short* __restrict__ hout, int nrows,
                     const int* __restrict__ edst, int* __restrict__ cnt, int ne,
                     int k, int histB) {
  __shared__ unsigned short sH[64 * 128];
  int oIdx, mIdx;
  if (role_other(blockIdx.x, k, histB, &oIdx, &mIdx)) {
    int i = oIdx * 256 + threadIdx.x;
    int stride = histB * 256;
    for (int e = i; e < ne; e += stride) atomicAdd(cnt + edst[e], 1);
    return;
  }
  mov_tile(mIdx * 64, sH, x, w1t, w2t, w3t, b1, b2, b3, hout, nrows);
}

// ---------------- K2: movB (remaining rows) interleaved with fill -----------
__global__ __launch_bounds__(256)
void mov_fill_kernel(const float* __restrict__ x,
                     const unsigned short* __restrict__ w1t,
                     const unsigned short* __restrict__ w2t,
                     const unsigned short* __restrict__ w3t,
                     const float* __restrict__ b1, const float* __restrict__ b2,
                     const float* __restrict__ b3,
                     unsigned short* __restrict__ hout, int nrows, int movABlocks,
                     const int* __restrict__ esrc, const int* __restrict__ edst,
                     int* __restrict__ cursor, int* __restrict__ csr, int ne,
                     int k, int fillB) {
  __shared__ unsigned short sH[64 * 128];
  int oIdx, mIdx;
  if (role_other(blockIdx.x, k, fillB, &oIdx, &mIdx)) {
    int i = oIdx * 256 + threadIdx.x;
    int stride = fillB * 256;
    for (int e = i; e < ne; e += stride) {
      int d = edst[e];
      int pos = atomicAdd(cursor + d, 1);
      csr[pos] = esrc[e];
    }
    return;
  }
  mov_tile((movABlocks + mIdx) * 64, sH, x, w1t, w2t, w3t, b1, b2, b3, hout, nrows);
}

// hierarchical scan: 1024 elems per block. s1: per-block sums.
__global__ __launch_bounds__(256)
void scan_sum_kernel(const int* __restrict__ cnt, int* __restrict__ bsum, int nph) {
  __shared__ int red[256];
  const int b = blockIdx.x, t = threadIdx.x;
  const int base = b * 1024 + t * 4;
  int s = 0;
#pragma unroll
  for (int i = 0; i < 4; ++i) {
    int idx = base + i;
    if (idx < nph) s += cnt[idx];
  }
  red[t] = s;
  __syncthreads();
  for (int d = 128; d > 0; d >>= 1) {
    if (t < d) red[t] += red[t + d];
    __syncthreads();
  }
  if (t == 0) bsum[b] = red[0];
}

__global__ __launch_bounds__(256)
void scan_top_kernel(const int* __restrict__ bsum, int* __restrict__ boff,
                     int* __restrict__ offs_end, int nb) {
  __shared__ int part[256];
  const int t = threadIdx.x;
  part[t] = (t < nb) ? bsum[t] : 0;
  __syncthreads();
  for (int d = 1; d < 256; d <<= 1) {
    int v = (t >= d) ? part[t - d] : 0;
    __syncthreads();
    part[t] += v;
    __syncthreads();
  }
  if (t < nb) boff[t] = (t == 0) ? 0 : part[t - 1];
  if (t == 255) *offs_end = part[255];
}

__global__ __launch_bounds__(256)
void scan_fill_kernel(const int* __restrict__ cnt, const int* __restrict__ boff,
                      int* __restrict__ offs, int* __restrict__ cursor, int nph) {
  __shared__ int part[256];
  const int b = blockIdx.x, t = threadIdx.x;
  const int base = b * 1024 + t * 4;
  int v[4];
  int s = 0;
#pragma unroll
  for (int i = 0; i < 4; ++i) {
    int idx = base + i;
    v[i] = (idx < nph) ? cnt[idx] : 0;
    s += v[i];
  }
  part[t] = s;
  __syncthreads();
  for (int d = 1; d < 256; d <<= 1) {
    int u = (t >= d) ? part[t - d] : 0;
    __syncthreads();
    part[t] += u;
    __syncthreads();
  }
  int run = boff[b] + ((t == 0) ? 0 : part[t - 1]);
#pragma unroll
  for (int i = 0; i < 4; ++i) {
    int idx = base + i;
    if (idx < nph) {
      offs[idx] = run;
      cursor[idx] = run;
      run += v[i];
    }
  }
}

// ---------------- per-phase gather-reduce with 4-edge ILP -------------------
__global__ __launch_bounds__(256)
void agg_kernel(const unsigned short* __restrict__ h, const int* __restrict__ csr,
                const int* __restrict__ offs, unsigned short* __restrict__ agg,
                int nph) {
  const int grp = threadIdx.x >> 5;
  const int l   = threadIdx.x & 31;
  const int ph  = blockIdx.x * 8 + grp;
  if (ph >= nph) return;
  const int beg = offs[ph], end = offs[ph + 1];

  f32x4 a0 = (f32x4)0.f, a1 = (f32x4)0.f, a2 = (f32x4)0.f, a3 = (f32x4)0.f;
  int j = beg;
  for (; j + 4 <= end; j += 4) {
    int s0 = csr[j], s1 = csr[j + 1], s2 = csr[j + 2], s3 = csr[j + 3];
    ushort4 v0 = *(const ushort4*)(h + (size_t)s0 * 128 + l * 4);
    ushort4 v1 = *(const ushort4*)(h + (size_t)s1 * 128 + l * 4);
    ushort4 v2 = *(const ushort4*)(h + (size_t)s2 * 128 + l * 4);
    ushort4 v3 = *(const ushort4*)(h + (size_t)s3 * 128 + l * 4);
    a0[0] += bf2f(v0.x); a0[1] += bf2f(v0.y); a0[2] += bf2f(v0.z); a0[3] += bf2f(v0.w);
    a1[0] += bf2f(v1.x); a1[1] += bf2f(v1.y); a1[2] += bf2f(v1.z); a1[3] += bf2f(v1.w);
    a2[0] += bf2f(v2.x); a2[1] += bf2f(v2.y); a2[2] += bf2f(v2.z); a2[3] += bf2f(v2.w);
    a3[0] += bf2f(v3.x); a3[1] += bf2f(v3.y); a3[2] += bf2f(v3.z); a3[3] += bf2f(v3.w);
  }
  for (; j < end; ++j) {
    int s = csr[j];
    ushort4 v = *(const ushort4*)(h + (size_t)s * 128 + l * 4);
    a0[0] += bf2f(v.x); a0[1] += bf2f(v.y); a0[2] += bf2f(v.z); a0[3] += bf2f(v.w);
  }
  const float sc = 1.f / (float)max(end - beg, 1);
  ushort4 o;
  o.x = f2bf((a0[0] + a1[0] + a2[0] + a3[0]) * sc);
  o.y = f2bf((a0[1] + a1[1] + a2[1] + a3[1]) * sc);
  o.z = f2bf((a0[2] + a1[2] + a2[2] + a3[2]) * sc);
  o.w = f2bf((a0[3] + a1[3] + a2[3] + a3[3]) * sc);
  *(ushort4*)(agg + (size_t)ph * 128 + l * 4) = o;
}

// ---------------- phase MLP via MFMA (unchanged) ----------------------------
__global__ __launch_bounds__(256)
void phase_mlp_mfma(const unsigned short* __restrict__ aggb,
                    const unsigned short* __restrict__ w4t,
                    const unsigned short* __restrict__ w5t,
                    const float* __restrict__ b4, const float* __restrict__ b5,
                    const float* __restrict__ W6, const float* __restrict__ b6,
                    float* __restrict__ logits, int nph) {
  __shared__ unsigned short sH[64 * 128];
  float* sPart = (float*)sH;
  const int tid  = threadIdx.x;
  const int lane = tid & 63;
  const int w    = tid >> 6;
  const int rloc = lane & 15;
  const int g    = lane >> 4;
  const int r0w  = (w & 1) * 32;
  const int c0   = (w >> 1) * 64;
  const int rowBlk = blockIdx.x * 64;

  f32x4 acc[2][4];
  short8 Bf[4][4];

#pragma unroll
  for (int ks = 0; ks < 4; ++ks)
#pragma unroll
    for (int cf = 0; cf < 4; ++cf)
      Bf[ks][cf] = *(const short8*)&w4t[(c0 + cf * 16 + rloc) * 128 + ks * 32 + g * 8];
#pragma unroll
  for (int rf = 0; rf < 2; ++rf)
#pragma unroll
    for (int cf = 0; cf < 4; ++cf) acc[rf][cf] = (f32x4)0.f;

  {
    const int row0 = rowBlk + r0w + rloc;
    const int row1 = row0 + 16;
#pragma unroll
    for (int ks = 0; ks < 4; ++ks) {
      short8 A0 = (short8)0, A1 = (short8)0;
      if (row0 < nph) A0 = *(const short8*)&aggb[(size_t)row0 * 128 + ks * 32 + g * 8];
      if (row1 < nph) A1 = *(const short8*)&aggb[(size_t)row1 * 128 + ks * 32 + g * 8];
#pragma unroll
      for (int cf = 0; cf < 4; ++cf) {
        acc[0][cf] = __builtin_amdgcn_mfma_f32_16x16x32_bf16(A0, Bf[ks][cf], acc[0][cf], 0, 0, 0);
        acc[1][cf] = __builtin_amdgcn_mfma_f32_16x16x32_bf16(A1, Bf[ks][cf], acc[1][cf], 0, 0, 0);
      }
    }
  }

  {
    float bv[4];
#pragma unroll
    for (int cf = 0; cf < 4; ++cf) bv[cf] = b4[c0 + cf * 16 + rloc];
#pragma unroll
    for (int rf = 0; rf < 2; ++rf)
#pragma unroll
      for (int cf = 0; cf < 4; ++cf)
#pragma unroll
        for (int i = 0; i < 4; ++i) {
          int row = r0w + rf * 16 + g * 4 + i;
          int col = c0 + cf * 16 + rloc;
          float v = fmaxf(acc[rf][cf][i] + bv[cf], 0.f);
          sH[row * 128 + (((col >> 3) ^ (row & 7)) << 3) + (col & 7)] = f2bf(v);
        }
  }
  __syncthreads();

#pragma unroll
  for (int ks = 0; ks < 4; ++ks)
#pragma unroll
    for (int cf = 0; cf < 4; ++cf)
      Bf[ks][cf] = *(const short8*)&w5t[(c0 + cf * 16 + rloc) * 128 + ks * 32 + g * 8];
#pragma unroll
  for (int rf = 0; rf < 2; ++rf)
#pragma unroll
    for (int cf = 0; cf < 4; ++cf) acc[rf][cf] = (f32x4)0.f;

#pragma unroll
  for (int ks = 0; ks < 4; ++ks) {
    short8 A0, A1;
    {
      int row = r0w + rloc;
      int slot = (ks * 4 + g) ^ (row & 7);
      A0 = *(const short8*)&sH[row * 128 + slot * 8];
    }
    {
      int row = r0w + 16 + rloc;
      int slot = (ks * 4 + g) ^ (row & 7);
      A1 = *(const short8*)&sH[row * 128 + slot * 8];
    }
#pragma unroll
    for (int cf = 0; cf < 4; ++cf) {
      acc[0][cf] = __builtin_amdgcn_mfma_f32_16x16x32_bf16(A0, Bf[ks][cf], acc[0][cf], 0, 0, 0);
      acc[1][cf] = __builtin_amdgcn_mfma_f32_16x16x32_bf16(A1, Bf[ks][cf], acc[1][cf], 0, 0, 0);
    }
  }

  float part8[2][4];
  {
    float bv[4], wv[4];
#pragma unroll
    for (int cf = 0; cf < 4; ++cf) {
      bv[cf] = b5[c0 + cf * 16 + rloc];
      wv[cf] = W6[c0 + cf * 16 + rloc];
    }
#pragma unroll
    for (int rf = 0; rf < 2; ++rf)
#pragma unroll
      for (int i = 0; i < 4; ++i) {
        float p = 0.f;
#pragma unroll
        for (int cf = 0; cf < 4; ++cf)
          p += fmaxf(acc[rf][cf][i] + bv[cf], 0.f) * wv[cf];
        part8[rf][i] = p;
      }
  }
#pragma unroll
  for (int m = 1; m < 16; m <<= 1) {
#pragma unroll
    for (int rf = 0; rf < 2; ++rf)
#pragma unroll
      for (int i = 0; i < 4; ++i)
        part8[rf][i] += __shfl_xor(part8[rf][i], m, 64);
  }
  __syncthreads();
  if (rloc == 0) {
#pragma unroll
    for (int rf = 0; rf < 2; ++rf)
#pragma unroll
      for (int i = 0; i < 4; ++i)
        sPart[(w >> 1) * 64 + r0w + rf * 16 + g * 4 + i] = part8[rf][i];
  }
  __syncthreads();
  if (tid < 64) {
    int gr = rowBlk + tid;
    if (gr < nph) logits[gr] = sPart[tid] + sPart[64 + tid] + b6[0];
  }
}

// ---------------------------------------------------------------------------
extern "C" void kernel_launch(void* const* d_in, const int* in_sizes, int n_in,
                              void* d_out, int out_size, void* d_ws, size_t ws_size,
                              hipStream_t stream) {
  const float* x  = (const float*)d_in[0];
  const float* W1 = (const float*)d_in[1];
  const float* b1 = (const float*)d_in[2];
  const float* W2 = (const float*)d_in[3];
  const float* b2 = (const float*)d_in[4];
  const float* W3 = (const float*)d_in[5];
  const float* b3 = (const float*)d_in[6];
  const float* W4 = (const float*)d_in[7];
  const float* b4 = (const float*)d_in[8];
  const float* W5 = (const float*)d_in[9];
  const float* b5 = (const float*)d_in[10];
  const float* W6 = (const float*)d_in[11];
  const float* b6 = (const float*)d_in[12];
  const int* esrc = (const int*)d_in[13];
  const int* edst = (const int*)d_in[14];

  const int nmov = in_sizes[0] / 16;
  const int ne   = in_sizes[13];
  const int nph  = out_size;

  char* ws = (char*)d_ws;
  size_t off = 0;
  auto take = [&](size_t bytes) {
    char* p = ws + off;
    off = (off + bytes + 255) & ~(size_t)255;
    return p;
  };
  unsigned short* hbuf = (unsigned short*)take((size_t)nmov * 128 * 2); // 128 MB
  int* csr             = (int*)take((size_t)ne * 4);                   //   4 MB
  int* cnt             = (int*)take((size_t)nph * 4);
  int* offs            = (int*)take(((size_t)nph + 1) * 4);
  int* cursor          = (int*)take((size_t)nph * 4);
  unsigned short* aggb = (unsigned short*)take((size_t)nph * 128 * 2); //  32 MB
  unsigned short* w1t  = (unsigned short*)take(128 * 32 * 2);
  unsigned short* w2t  = (unsigned short*)take(128 * 128 * 2);
  unsigned short* w3t  = (unsigned short*)take(128 * 128 * 2);
  unsigned short* w4t  = (unsigned short*)take(128 * 128 * 2);
  unsigned short* w5t  = (unsigned short*)take(128 * 128 * 2);
  const int nb = (nph + 1023) / 1024;
  int* bsum            = (int*)take((size_t)nb * 4);
  int* boff            = (int*)take((size_t)nb * 4);
  if (off > ws_size) return;

  (void)hipMemsetAsync(cnt, 0, (size_t)nph * 4, stream);

  prep_weights<<<64, 256, 0, stream>>>(W1, W2, W3, W4, W5, w1t, w2t, w3t, w4t, w5t);

  const int movBlocks = (nmov + 63) / 64;
  const int movA = (movBlocks * 5) / 8;          // 5/8 of rows with hist
  const int movB = movBlocks - movA;             // 3/8 of rows with fill

  // K1: movA interleaved with hist
  const int histB = 1024;
  {
    const int N1 = movA + histB;
    int k1 = N1 / histB;                         // floor -> histB*k1 <= N1
    if (k1 < 2) k1 = 2;
    mov_hist_kernel<<<N1, 256, 0, stream>>>(
        x, w1t, w2t, w3t, b1, b2, b3, hbuf, nmov, edst, cnt, ne, k1, histB);
  }

  scan_sum_kernel<<<nb, 256, 0, stream>>>(cnt, bsum, nph);
  scan_top_kernel<<<1, 256, 0, stream>>>(bsum, boff, offs + nph, nb);
  scan_fill_kernel<<<nb, 256, 0, stream>>>(cnt, boff, offs, cursor, nph);

  // K2: movB interleaved with fill
  const int fillB = 1024;
  {
    const int N2 = movB + fillB;
    int k2 = N2 / fillB;
    if (k2 < 2) k2 = 2;
    mov_fill_kernel<<<N2, 256, 0, stream>>>(
        x, w1t, w2t, w3t, b1, b2, b3, hbuf, nmov, movA,
        esrc, edst, cursor, csr, ne, k2, fillB);
  }

  int aggBlocks = (nph + 7) / 8;
  agg_kernel<<<aggBlocks, 256, 0, stream>>>(hbuf, csr, offs, aggb, nph);

  int phBlocks = (nph + 63) / 64;
  phase_mlp_mfma<<<phBlocks, 256, 0, stream>>>(aggb, w4t, w5t, b4, b5, W6, b6,
                                               (float*)d_out, nph);
}